// Round 4
// baseline (48.101 us; speedup 1.0000x reference)
//
#include <hip/hip_runtime.h>
#include <math.h>

#define NR 8192
#define NC 8192
#define EE 64
#define LOG2E   1.4426950408889634f
#define LN2     0.6931471805599453f
#define KSCALE  (-2.0f * LOG2E)        // folded into Xs
#define C18     (18.0f * LOG2E)        // folded into MFMA C-init
#define NSPLIT  32                     // col splits in main
#define CPS     (NC / NSPLIT)          // 256 cols per split

typedef __attribute__((ext_vector_type(8))) short bf16x8;
typedef __attribute__((ext_vector_type(4))) float f32x4;

__device__ __forceinline__ float bf2f(unsigned short u) {
    unsigned int x = ((unsigned int)u) << 16;
    return __builtin_bit_cast(float, x);
}
__device__ __forceinline__ unsigned short f2bf(float f) {
    unsigned int u = __builtin_bit_cast(unsigned int, f);
    u += 0x7FFFu + ((u >> 16) & 1u);
    return (unsigned short)(u >> 16);
}

// ---------------------------------------------------------------------------
// K1: L2-normalize (x3) rows of X and proxies -> bf16.
// X rows are pre-scaled by -2*log2e (Xs); proxies plain (Pb).
// ||row||^2 == 9 exactly -> x_sq/p_sq are compile-time constants (9).
// Also zeroes the finalize ticket (stream-ordered before K3 reads it).
// ---------------------------------------------------------------------------
__global__ __launch_bounds__(256) void norm_kernel(
    const float* __restrict__ X, const float* __restrict__ P,
    unsigned short* __restrict__ Xs, unsigned short* __restrict__ Pb,
    int* __restrict__ ticket)
{
    if (blockIdx.x == 0 && threadIdx.x == 0) *ticket = 0;
    int row  = blockIdx.x * 4 + (threadIdx.x >> 6);
    int lane = threadIdx.x & 63;
    bool isX = row < NR;
    int r = isX ? row : row - NR;
    const float* src = isX ? X : P;
    float v = src[(size_t)r * EE + lane];
    float s = v * v;
    #pragma unroll
    for (int off = 32; off; off >>= 1) s += __shfl_xor(s, off);
    float xn = v * (3.0f * rsqrtf(s));
    if (isX)
        Xs[(size_t)r * EE + lane] = f2bf(xn * KSCALE);
    else
        Pb[(size_t)r * EE + lane] = f2bf(xn);
}

// ---------------------------------------------------------------------------
// K2: MFMA GEMM + exp epilogue.
// d = mfma(Xs, Pb, C18) = log2e*(18 - 2*dot)
//   accE += exp2(d)   (sum of exp(D), no max-sub: D <= 36, no overflow)
//   accD += d         (recovers sumD = dsum*ln2 in finalize)
// Block = 4 waves; wave w owns rows r0+w*64 (A frags in regs); all waves
// share the SAME 256-col B slice (L1 reuse). No LDS, no atomics, no init.
// Per-split partials packed: part[row][s] = e-part, part[row][32+s] = d-part.
// Grid: (32 row panels, 32 col splits) = 1024 blocks = 4/CU.
// ---------------------------------------------------------------------------
__global__ __launch_bounds__(256) void main_kernel(
    const unsigned short* __restrict__ Xs, const unsigned short* __restrict__ Pb,
    float* __restrict__ part)
{
    const int tid = threadIdx.x;
    const int w  = tid >> 6, l = tid & 63;
    const int lr = l & 15, lg = l >> 4;
    const int r0 = blockIdx.x * 256 + w * 64;
    const int cbase = blockIdx.y * CPS;
    const int s = blockIdx.y;

    bf16x8 a[4][2];
    #pragma unroll
    for (int rt = 0; rt < 4; ++rt)
        #pragma unroll
        for (int kk = 0; kk < 2; ++kk)
            a[rt][kk] = *reinterpret_cast<const bf16x8*>(
                Xs + (size_t)(r0 + rt * 16 + lr) * EE + kk * 32 + lg * 8);

    float accE[4][4] = {};
    float accD[4][4] = {};
    const f32x4 dinit = {C18, C18, C18, C18};

    #pragma unroll 2
    for (int j = 0; j < CPS / 16; ++j) {
        const int c0 = cbase + j * 16;
        const size_t bb = (size_t)(c0 + lr) * EE + lg * 8;
        bf16x8 b0 = *reinterpret_cast<const bf16x8*>(Pb + bb);
        bf16x8 b1 = *reinterpret_cast<const bf16x8*>(Pb + bb + 32);
        #pragma unroll
        for (int rt = 0; rt < 4; ++rt) {
            f32x4 d = dinit;
            d = __builtin_amdgcn_mfma_f32_16x16x32_bf16(a[rt][0], b0, d, 0, 0, 0);
            d = __builtin_amdgcn_mfma_f32_16x16x32_bf16(a[rt][1], b1, d, 0, 0, 0);
            // D layout: col = lane&15, row = (lane>>4)*4 + q
            #pragma unroll
            for (int q = 0; q < 4; ++q) {
                accE[rt][q] += __builtin_exp2f(d[q]);
                accD[rt][q] += d[q];
            }
        }
    }

    #pragma unroll
    for (int rt = 0; rt < 4; ++rt)
        #pragma unroll
        for (int q = 0; q < 4; ++q) {
            float ve = accE[rt][q];
            float vd = accD[rt][q];
            ve += __shfl_xor(ve, 1);  vd += __shfl_xor(vd, 1);
            ve += __shfl_xor(ve, 2);  vd += __shfl_xor(vd, 2);
            ve += __shfl_xor(ve, 4);  vd += __shfl_xor(vd, 4);
            ve += __shfl_xor(ve, 8);  vd += __shfl_xor(vd, 8);
            if (lr == 0) {
                const size_t row = r0 + rt * 16 + lg * 4 + q;
                part[row * 64 + s]      = ve;
                part[row * 64 + 32 + s] = vd;
            }
        }
}

// ---------------------------------------------------------------------------
// K3: finalize. 128 blocks x 1024 thr, 64 rows/block.
// term_i = log(es_i) - [0.9*Dt_i + (0.1/8191)*(sumD_i - Dt_i)]
//   Dt_i   = 18 + dot(Xs_i, Pb_{T_i}) * ln2
//   sumD_i = dsum_i * ln2
// Per-block partial -> lossPart[b]; last block (ticket) reduces -> out.
// ---------------------------------------------------------------------------
__global__ __launch_bounds__(1024) void final_kernel(
    const unsigned short* __restrict__ Xs, const unsigned short* __restrict__ Pb,
    const int* __restrict__ T, const float* __restrict__ part,
    float* __restrict__ lossPart, int* __restrict__ ticket,
    float* __restrict__ out)
{
    __shared__ float terms[16];
    __shared__ int   isLast;
    __shared__ float red2[2];
    int wid = threadIdx.x >> 6, lane = threadIdx.x & 63;

    float wsum = 0.f;
    #pragma unroll
    for (int rr = 0; rr < 4; ++rr) {
        int row = blockIdx.x * 64 + wid * 4 + rr;
        int t = T[row];
        float xs = bf2f(Xs[(size_t)row * EE + lane]);
        float pt = bf2f(Pb[(size_t)t  * EE + lane]);
        float d1 = xs * pt;                       // -> dot_s
        float pv = part[(size_t)row * 64 + lane]; // halves: e | d
        #pragma unroll
        for (int off = 1; off <= 16; off <<= 1) {
            d1 += __shfl_xor(d1, off);
            pv += __shfl_xor(pv, off);
        }
        d1 += __shfl_xor(d1, 32);
        float other = __shfl_xor(pv, 32);
        if (lane == 0) {
            float es   = pv;
            float ds   = other;
            float Dt   = 18.0f + d1 * LN2;
            float sumD = ds * LN2;
            float lse  = __logf(es);
            wsum += lse - (0.9f * Dt + (0.1f / 8191.0f) * (sumD - Dt));
        }
    }
    if (lane == 0) terms[wid] = wsum;
    __syncthreads();
    if (threadIdx.x == 0) {
        float sB = 0.f;
        #pragma unroll
        for (int i = 0; i < 16; ++i) sB += terms[i];
        lossPart[blockIdx.x] = sB;
        __threadfence();
        int old = atomicAdd(ticket, 1);
        isLast = (old == 127) ? 1 : 0;
    }
    __syncthreads();
    if (isLast) {
        // last arriver: all 128 partials are globally visible; reduce them.
        if (threadIdx.x < 128) {
            float v = atomicAdd((float*)&lossPart[threadIdx.x], 0.0f); // L2 read
            #pragma unroll
            for (int off = 32; off; off >>= 1) v += __shfl_xor(v, off);
            if ((threadIdx.x & 63) == 0) red2[threadIdx.x >> 6] = v;
        }
        __syncthreads();
        if (threadIdx.x == 0)
            out[0] = (red2[0] + red2[1]) * (1.0f / (float)NR);
    }
}

// ---------------------------------------------------------------------------
extern "C" void kernel_launch(void* const* d_in, const int* in_sizes, int n_in,
                              void* d_out, int out_size, void* d_ws, size_t ws_size,
                              hipStream_t stream)
{
    const float* X = (const float*)d_in[0];
    const int*   T = (const int*)d_in[1];
    const float* P = (const float*)d_in[2];

    unsigned short* Xs = (unsigned short*)d_ws;                 // 1 MB
    unsigned short* Pb = Xs + (size_t)NR * EE;                  // 1 MB
    float* part     = (float*)(Pb + (size_t)NC * EE);           // 2 MB
    float* lossPart = part + (size_t)NR * 64;                   // 512 B
    int*   ticket   = (int*)(lossPart + 128);
    float* out      = (float*)d_out;

    norm_kernel<<<(NR + NC) / 4, 256, 0, stream>>>(X, P, Xs, Pb, ticket);
    main_kernel<<<dim3(NR / 256, NSPLIT), 256, 0, stream>>>(Xs, Pb, part);
    final_kernel<<<NR / 64, 1024, 0, stream>>>(Xs, Pb, T, part, lossPart, ticket, out);
}